// Round 1
// baseline (344.169 us; speedup 1.0000x reference)
//
#include <hip/hip_runtime.h>

#define HID 896
#define NQ 896
#define NKV 128
#define NQKV 1152
#define NH 14
#define NKVH 2
#define GQ 7
#define DH 64
#define SEQ 2048
#define BATCH 2
#define TOK (BATCH*SEQ)

typedef __attribute__((ext_vector_type(8))) short short8;    // 8 bf16 (4 VGPRs)
typedef __attribute__((ext_vector_type(4))) float f32x4;
typedef __attribute__((ext_vector_type(4))) unsigned short us4;

__device__ __forceinline__ unsigned short f2bf(float x) {
  unsigned int u = __builtin_bit_cast(unsigned int, x);
  u = (u + 0x7fffu + ((u >> 16) & 1u)) >> 16;
  return (unsigned short)u;
}
__device__ __forceinline__ float bf2f(unsigned short b) {
  return __builtin_bit_cast(float, (unsigned int)b << 16);
}
__device__ __forceinline__ f32x4 fzero4() {
  f32x4 z; z[0]=0.f; z[1]=0.f; z[2]=0.f; z[3]=0.f; return z;
}
__device__ __forceinline__ void gload_lds16(const unsigned short* g, unsigned short* l) {
  __builtin_amdgcn_global_load_lds(
      (const __attribute__((address_space(1))) void*)(const void*)g,
      (__attribute__((address_space(3))) void*)(void*)l, 16, 0, 0);
}

// ---------------- conversion kernels ----------------

__global__ void k_cvt(const float4* __restrict__ in, us4* __restrict__ out, int n4) {
  int i = blockIdx.x * blockDim.x + threadIdx.x;
  if (i >= n4) return;
  float4 v = in[i];
  us4 o; o[0]=f2bf(v.x); o[1]=f2bf(v.y); o[2]=f2bf(v.z); o[3]=f2bf(v.w);
  out[i] = o;
}

// W [K][N] fp32 -> out [N][K] bf16, 64x64 tiles via LDS
__global__ void k_transpose_cvt(const float* __restrict__ W, unsigned short* __restrict__ out,
                                int K, int N) {
  __shared__ unsigned short Ls[64*65];
  int n0 = blockIdx.x * 64, k0 = blockIdx.y * 64;
  int tid = threadIdx.x;
  #pragma unroll
  for (int i = 0; i < 16; ++i) {
    int idx = i*256 + tid;
    int r = idx >> 6, c = idx & 63;
    Ls[c*65 + r] = f2bf(W[(size_t)(k0 + r)*N + n0 + c]);
  }
  __syncthreads();
  #pragma unroll
  for (int i = 0; i < 16; ++i) {
    int idx = i*256 + tid;
    int r2 = idx >> 6, c2 = idx & 63;
    out[(size_t)(n0 + r2)*K + k0 + c2] = Ls[r2*65 + c2];
  }
}

__global__ void k_bias(const float* __restrict__ bq, const float* __restrict__ bk,
                       const float* __restrict__ bv, float* __restrict__ out) {
  int i = blockIdx.x * blockDim.x + threadIdx.x;
  if (i >= NQKV) return;
  if (i < NQ) out[i] = bq[i];
  else if (i < NQ + NKV) out[i] = bk[i - NQ];
  else out[i] = bv[i - NQ - NKV];
}

__global__ void k_tables(float* __restrict__ ct, float* __restrict__ st) {
  int i = blockIdx.x * blockDim.x + threadIdx.x;  // SEQ*32
  int s = i >> 5, dp = i & 31;
  float inv = __expf(-(float)(2*dp) * (13.815510557964274f / 64.0f)); // theta^(-2dp/64)
  float f = (float)s * inv;
  ct[i] = cosf(f); st[i] = sinf(f);
}

// ---------------- GEMM: C[M][N] = A[M][K] @ Bt[N][K]^T (bf16 in, fp32 acc) ----------------
// OUTMODE 0: bf16 out + bias; OUTMODE 1: fp32 out
template<int OUTMODE>
__global__ __launch_bounds__(256, 2) void k_gemm_bt(
    const unsigned short* __restrict__ A,
    const unsigned short* __restrict__ Bt,
    const float* __restrict__ bias,
    void* __restrict__ Cout,
    int M, int N, int K) {
  __shared__ unsigned short As[128*64];
  __shared__ unsigned short Bs[128*64];
  int tid = threadIdx.x;
  int lane = tid & 63, w = tid >> 6;
  int wr = w >> 1, wc = w & 1;
  int l15 = lane & 15, l4 = lane >> 4;
  int m0 = blockIdx.y * 128, n0 = blockIdx.x * 128;

  f32x4 acc[4][4];
  #pragma unroll
  for (int i = 0; i < 4; ++i)
    #pragma unroll
    for (int j = 0; j < 4; ++j) acc[i][j] = fzero4();

  int nkt = K >> 6;
  for (int kt = 0; kt < nkt; ++kt) {
    int k0 = kt << 6;
    // stage A,B tiles: 1024 16B chunks each; pre-swizzled global source, linear LDS dest
    #pragma unroll
    for (int t = 0; t < 4; ++t) {
      int chunk = t*256 + w*64 + lane;
      int row = chunk >> 3, sp = chunk & 7;
      int sl = sp ^ (row & 7);
      gload_lds16(A + (size_t)(m0+row)*K + k0 + sl*8, &As[(t*256 + w*64)*8]);
      gload_lds16(Bt + (size_t)(n0+row)*K + k0 + sl*8, &Bs[(t*256 + w*64)*8]);
    }
    __syncthreads();
    #pragma unroll
    for (int s = 0; s < 2; ++s) {
      short8 af[4], bfr[4];
      #pragma unroll
      for (int mi = 0; mi < 4; ++mi) {
        int row = wr*64 + mi*16 + l15;
        int slot = (s*4 + l4) ^ (row & 7);
        af[mi] = *reinterpret_cast<const short8*>(&As[row*64 + slot*8]);
      }
      #pragma unroll
      for (int ni = 0; ni < 4; ++ni) {
        int row = wc*64 + ni*16 + l15;
        int slot = (s*4 + l4) ^ (row & 7);
        bfr[ni] = *reinterpret_cast<const short8*>(&Bs[row*64 + slot*8]);
      }
      #pragma unroll
      for (int mi = 0; mi < 4; ++mi)
        #pragma unroll
        for (int ni = 0; ni < 4; ++ni)
          acc[mi][ni] = __builtin_amdgcn_mfma_f32_16x16x32_bf16(af[mi], bfr[ni], acc[mi][ni], 0, 0, 0);
    }
    __syncthreads();
  }
  // epilogue: C row=(l>>4)*4+r, col=l&15 per 16x16 frag
  #pragma unroll
  for (int mi = 0; mi < 4; ++mi) {
    #pragma unroll
    for (int ni = 0; ni < 4; ++ni) {
      #pragma unroll
      for (int r = 0; r < 4; ++r) {
        int row = m0 + wr*64 + mi*16 + l4*4 + r;
        int col = n0 + wc*64 + ni*16 + l15;
        float v = acc[mi][ni][r];
        if (OUTMODE == 0) {
          v += bias[col];
          ((unsigned short*)Cout)[(size_t)row*N + col] = f2bf(v);
        } else {
          ((float*)Cout)[(size_t)row*N + col] = v;
        }
      }
    }
  }
}

// ---------------- RoPE + layout ----------------
// qkv [TOK][1152] bf16 -> Qr [B][NH][S][64] (x0.125), Kr [B][NKVH][S][64], Vt [B][NKVH][64][S]
__global__ void k_rope(const unsigned short* __restrict__ qkv,
                       const float* __restrict__ ct, const float* __restrict__ st,
                       unsigned short* __restrict__ Qr, unsigned short* __restrict__ Kr,
                       unsigned short* __restrict__ Vt) {
  int t = blockIdx.x; int b = t >> 11; int s = t & 2047;
  int tid = threadIdx.x;
  const unsigned short* row = qkv + (size_t)t * NQKV;
  if (tid < 448) {
    int h = tid >> 5, dp = tid & 31;
    float x1 = bf2f(row[h*64 + dp]);
    float x2 = bf2f(row[h*64 + dp + 32]);
    float c = ct[s*32 + dp], sn = st[s*32 + dp];
    size_t base = (((size_t)b*NH + h)*SEQ + s)*64;
    Qr[base + dp]      = f2bf((x1*c - x2*sn) * 0.125f);
    Qr[base + dp + 32] = f2bf((x2*c + x1*sn) * 0.125f);
  } else {
    int j = tid - 448;
    int kvh = j >> 5, dp = j & 31;
    float x1 = bf2f(row[NQ + kvh*64 + dp]);
    float x2 = bf2f(row[NQ + kvh*64 + dp + 32]);
    float c = ct[s*32 + dp], sn = st[s*32 + dp];
    size_t base = (((size_t)b*NKVH + kvh)*SEQ + s)*64;
    Kr[base + dp]      = f2bf(x1*c - x2*sn);
    Kr[base + dp + 32] = f2bf(x2*c + x1*sn);
  }
  if (tid < 128) {
    int kvh = tid >> 6, d = tid & 63;
    Vt[(((size_t)b*NKVH + kvh)*64 + d)*SEQ + s] = row[1024 + kvh*64 + d];
  }
}

// ---------------- flash attention (causal, GQA) ----------------
// 4 waves/block, wave w owns q-rows [qt*64+w*16, +16). K/V read direct from global (L2-fit).
__global__ __launch_bounds__(256, 2) void k_attn(
    const unsigned short* __restrict__ Q,   // [B][NH][S][64], pre-scaled by 0.125
    const unsigned short* __restrict__ Kr,  // [B][NKVH][S][64]
    const unsigned short* __restrict__ Vt,  // [B][NKVH][64][S]
    unsigned short* __restrict__ Aout) {    // [TOK][896]
  __shared__ unsigned short P_lds[4*16*64];  // 8KB, 2KB per wave, XOR-swizzled
  int lane = threadIdx.x & 63, w = threadIdx.x >> 6;
  int l15 = lane & 15, l4 = lane >> 4;
  int qt = blockIdx.x, h = blockIdx.y, b = blockIdx.z;
  int kvh = h / GQ;
  const unsigned short* Qb = Q + (((size_t)(b*NH + h))*SEQ + qt*64 + w*16) * 64;
  const unsigned short* Kb = Kr + ((size_t)(b*NKVH + kvh))*SEQ*64;
  const unsigned short* Vb = Vt + ((size_t)(b*NKVH + kvh))*64*SEQ;

  short8 qa[2];
  #pragma unroll
  for (int s = 0; s < 2; ++s)
    qa[s] = *reinterpret_cast<const short8*>(Qb + l15*64 + s*32 + l4*8);

  f32x4 acc_o[4];
  #pragma unroll
  for (int n = 0; n < 4; ++n) acc_o[n] = fzero4();
  float m_run[4], l_run[4];
  #pragma unroll
  for (int r = 0; r < 4; ++r) { m_run[r] = -__builtin_inff(); l_run[r] = 0.0f; }

  unsigned short* Pw = &P_lds[w*16*64];
  int q_glob = qt*64 + w*16 + l4*4;   // + r

  int nkt = qt + 1;
  for (int kt = 0; kt < nkt; ++kt) {
    // scores: S = Q(16x64) @ K^T(64x64) -> 4 col-frags
    f32x4 sa[4];
    #pragma unroll
    for (int n = 0; n < 4; ++n) sa[n] = fzero4();
    #pragma unroll
    for (int s = 0; s < 2; ++s) {
      short8 kb[4];
      #pragma unroll
      for (int n = 0; n < 4; ++n)
        kb[n] = *reinterpret_cast<const short8*>(Kb + (size_t)(kt*64 + n*16 + l15)*64 + s*32 + l4*8);
      #pragma unroll
      for (int n = 0; n < 4; ++n)
        sa[n] = __builtin_amdgcn_mfma_f32_16x16x32_bf16(qa[s], kb[n], sa[n], 0, 0, 0);
    }
    if (kt == qt) {  // diagonal tile: causal mask
      #pragma unroll
      for (int n = 0; n < 4; ++n) {
        int kc = kt*64 + n*16 + l15;
        #pragma unroll
        for (int r = 0; r < 4; ++r)
          if (kc > q_glob + r) sa[n][r] = -1e30f;
      }
    }
    // online softmax (wave-parallel, width-16 shuffle reduce) + P -> LDS (bf16, swizzled)
    #pragma unroll
    for (int r = 0; r < 4; ++r) {
      float tmax = fmaxf(fmaxf(sa[0][r], sa[1][r]), fmaxf(sa[2][r], sa[3][r]));
      tmax = fmaxf(tmax, __shfl_xor(tmax, 1, 16));
      tmax = fmaxf(tmax, __shfl_xor(tmax, 2, 16));
      tmax = fmaxf(tmax, __shfl_xor(tmax, 4, 16));
      tmax = fmaxf(tmax, __shfl_xor(tmax, 8, 16));
      float mn = fmaxf(m_run[r], tmax);
      float sc = __expf(m_run[r] - mn);
      float pv[4]; float sum = 0.0f;
      #pragma unroll
      for (int n = 0; n < 4; ++n) { pv[n] = __expf(sa[n][r] - mn); sum += pv[n]; }
      sum += __shfl_xor(sum, 1, 16);
      sum += __shfl_xor(sum, 2, 16);
      sum += __shfl_xor(sum, 4, 16);
      sum += __shfl_xor(sum, 8, 16);
      m_run[r] = mn;
      l_run[r] = l_run[r]*sc + sum;
      #pragma unroll
      for (int n = 0; n < 4; ++n) acc_o[n][r] *= sc;
      int prow = l4*4 + r;
      #pragma unroll
      for (int n = 0; n < 4; ++n) {
        int colbyte = n*32 + l15*2;
        int pb = prow*128 + ((((colbyte >> 4) ^ (prow & 7))) << 4) + (colbyte & 15);
        Pw[pb >> 1] = f2bf(pv[n]);
      }
    }
    __syncthreads();
    // PV: O += P(16x64) @ V(64x64); A-frags from swizzled LDS, B-frags from Vt global
    #pragma unroll
    for (int s2 = 0; s2 < 2; ++s2) {
      int slot = (s2*4 + l4) ^ (l15 & 7);
      short8 pa = *reinterpret_cast<const short8*>(&Pw[(l15*128 + (slot << 4)) >> 1]);
      #pragma unroll
      for (int n = 0; n < 4; ++n) {
        short8 vb = *reinterpret_cast<const short8*>(Vb + (size_t)(n*16 + l15)*SEQ + kt*64 + s2*32 + l4*8);
        acc_o[n] = __builtin_amdgcn_mfma_f32_16x16x32_bf16(pa, vb, acc_o[n], 0, 0, 0);
      }
    }
    __syncthreads();
  }
  // epilogue
  #pragma unroll
  for (int r = 0; r < 4; ++r) {
    float inv = 1.0f / l_run[r];
    size_t tok = (size_t)b*SEQ + q_glob + r;
    #pragma unroll
    for (int n = 0; n < 4; ++n)
      Aout[tok*NQ + h*64 + n*16 + l15] = f2bf(acc_o[n][r] * inv);
  }
}

// ---------------- launcher ----------------
extern "C" void kernel_launch(void* const* d_in, const int* in_sizes, int n_in,
                              void* d_out, int out_size, void* d_ws, size_t ws_size,
                              hipStream_t stream) {
  const float* hs = (const float*)d_in[0];
  const float* wq = (const float*)d_in[1];
  const float* bq = (const float*)d_in[2];
  const float* wk = (const float*)d_in[3];
  const float* bk = (const float*)d_in[4];
  const float* wv = (const float*)d_in[5];
  const float* bv = (const float*)d_in[6];
  const float* wo = (const float*)d_in[7];
  float* out = (float*)d_out;

  char* p = (char*)d_ws;
  auto alloc = [&](size_t bytes) { char* r = p; p += (bytes + 255) & ~(size_t)255; return r; };
  unsigned short* hb    = (unsigned short*)alloc((size_t)TOK*HID*2);
  unsigned short* wqkvt = (unsigned short*)alloc((size_t)NQKV*HID*2);
  unsigned short* wot   = (unsigned short*)alloc((size_t)HID*NQ*2);
  float*          bqkv  = (float*)alloc(NQKV*4);
  unsigned short* qkvt  = (unsigned short*)alloc((size_t)TOK*NQKV*2);
  unsigned short* q_r   = (unsigned short*)alloc((size_t)BATCH*NH*SEQ*DH*2);
  unsigned short* k_r   = (unsigned short*)alloc((size_t)BATCH*NKVH*SEQ*DH*2);
  unsigned short* v_t   = (unsigned short*)alloc((size_t)BATCH*NKVH*DH*SEQ*2);
  float*          ct    = (float*)alloc((size_t)SEQ*32*4);
  float*          st    = (float*)alloc((size_t)SEQ*32*4);
  unsigned short* attn  = hb;  // reuse: hb dead after GEMM1

  k_cvt<<<TOK*HID/4/256, 256, 0, stream>>>((const float4*)hs, (us4*)hb, TOK*HID/4);
  k_transpose_cvt<<<dim3(NQ/64, HID/64), 256, 0, stream>>>(wq, wqkvt, HID, NQ);
  k_transpose_cvt<<<dim3(NKV/64, HID/64), 256, 0, stream>>>(wk, wqkvt + (size_t)NQ*HID, HID, NKV);
  k_transpose_cvt<<<dim3(NKV/64, HID/64), 256, 0, stream>>>(wv, wqkvt + (size_t)(NQ+NKV)*HID, HID, NKV);
  k_transpose_cvt<<<dim3(HID/64, NQ/64), 256, 0, stream>>>(wo, wot, NQ, HID);
  k_bias<<<5, 256, 0, stream>>>(bq, bk, bv, bqkv);
  k_tables<<<SEQ*32/256, 256, 0, stream>>>(ct, st);

  k_gemm_bt<0><<<dim3(NQKV/128, TOK/128), 256, 0, stream>>>(hb, wqkvt, bqkv, qkvt, TOK, NQKV, HID);
  k_rope<<<TOK, 512, 0, stream>>>(qkvt, ct, st, q_r, k_r, v_t);
  k_attn<<<dim3(SEQ/64, NH, BATCH), 256, 0, stream>>>(q_r, k_r, v_t, attn);
  k_gemm_bt<1><<<dim3(NQ/128, TOK/128), 256, 0, stream>>>(attn, wot, nullptr, out, TOK, NQ, HID);
}

// Round 2
// 175.660 us; speedup vs baseline: 1.9593x; 1.9593x over previous
//
#include <hip/hip_runtime.h>

#define HID 896
#define NQ 896
#define NKV 128
#define NQKV 1152
#define NH 14
#define NKVH 2
#define GQ 7
#define DH 64
#define SEQ 2048
#define BATCH 2
#define TOK (BATCH*SEQ)

typedef __attribute__((ext_vector_type(8))) short short8;    // 8 bf16 (4 VGPRs)
typedef __attribute__((ext_vector_type(4))) float f32x4;
typedef __attribute__((ext_vector_type(4))) unsigned short us4;

__device__ __forceinline__ unsigned short f2bf(float x) {
  unsigned int u = __builtin_bit_cast(unsigned int, x);
  u = (u + 0x7fffu + ((u >> 16) & 1u)) >> 16;
  return (unsigned short)u;
}
__device__ __forceinline__ float bf2f(unsigned short b) {
  return __builtin_bit_cast(float, (unsigned int)b << 16);
}
__device__ __forceinline__ f32x4 fzero4() {
  f32x4 z; z[0]=0.f; z[1]=0.f; z[2]=0.f; z[3]=0.f; return z;
}
__device__ __forceinline__ void gload_lds16(const unsigned short* g, unsigned short* l) {
  __builtin_amdgcn_global_load_lds(
      (const __attribute__((address_space(1))) void*)(const void*)g,
      (__attribute__((address_space(3))) void*)(void*)l, 16, 0, 0);
}

// ---------------- conversion kernels ----------------

__global__ void k_cvt(const float4* __restrict__ in, us4* __restrict__ out, int n4) {
  int i = blockIdx.x * blockDim.x + threadIdx.x;
  if (i >= n4) return;
  float4 v = in[i];
  us4 o; o[0]=f2bf(v.x); o[1]=f2bf(v.y); o[2]=f2bf(v.z); o[3]=f2bf(v.w);
  out[i] = o;
}

// W [K][N] fp32 -> out [N][K] bf16, 64x64 tiles via LDS
__global__ void k_transpose_cvt(const float* __restrict__ W, unsigned short* __restrict__ out,
                                int K, int N) {
  __shared__ unsigned short Ls[64*65];
  int n0 = blockIdx.x * 64, k0 = blockIdx.y * 64;
  int tid = threadIdx.x;
  #pragma unroll
  for (int i = 0; i < 16; ++i) {
    int idx = i*256 + tid;
    int r = idx >> 6, c = idx & 63;
    Ls[c*65 + r] = f2bf(W[(size_t)(k0 + r)*N + n0 + c]);
  }
  __syncthreads();
  #pragma unroll
  for (int i = 0; i < 16; ++i) {
    int idx = i*256 + tid;
    int r2 = idx >> 6, c2 = idx & 63;
    out[(size_t)(n0 + r2)*K + k0 + c2] = Ls[r2*65 + c2];
  }
}

__global__ void k_bias(const float* __restrict__ bq, const float* __restrict__ bk,
                       const float* __restrict__ bv, float* __restrict__ out) {
  int i = blockIdx.x * blockDim.x + threadIdx.x;
  if (i >= NQKV) return;
  if (i < NQ) out[i] = bq[i];
  else if (i < NQ + NKV) out[i] = bk[i - NQ];
  else out[i] = bv[i - NQ - NKV];
}

__global__ void k_tables(float* __restrict__ ct, float* __restrict__ st) {
  int i = blockIdx.x * blockDim.x + threadIdx.x;  // SEQ*32
  int s = i >> 5, dp = i & 31;
  float inv = __expf(-(float)(2*dp) * (13.815510557964274f / 64.0f)); // theta^(-2dp/64)
  float f = (float)s * inv;
  ct[i] = cosf(f); st[i] = sinf(f);
}

// ---------------- GEMM: C[M][N] = A[M][K] @ Bt[N][K]^T (bf16 in, fp32 acc) ----------------
// OUTMODE 0: bf16 out + bias; OUTMODE 1: fp32 out
template<int OUTMODE>
__global__ __launch_bounds__(256, 2) void k_gemm_bt(
    const unsigned short* __restrict__ A,
    const unsigned short* __restrict__ Bt,
    const float* __restrict__ bias,
    void* __restrict__ Cout,
    int M, int N, int K) {
  __shared__ unsigned short As[128*64];
  __shared__ unsigned short Bs[128*64];
  int tid = threadIdx.x;
  int lane = tid & 63, w = tid >> 6;
  int wr = w >> 1, wc = w & 1;
  int l15 = lane & 15, l4 = lane >> 4;
  int m0 = blockIdx.y * 128, n0 = blockIdx.x * 128;

  f32x4 acc[4][4];
  #pragma unroll
  for (int i = 0; i < 4; ++i)
    #pragma unroll
    for (int j = 0; j < 4; ++j) acc[i][j] = fzero4();

  int nkt = K >> 6;
  for (int kt = 0; kt < nkt; ++kt) {
    int k0 = kt << 6;
    // stage A,B tiles: 1024 16B chunks each; pre-swizzled global source, linear LDS dest
    #pragma unroll
    for (int t = 0; t < 4; ++t) {
      int chunk = t*256 + w*64 + lane;
      int row = chunk >> 3, sp = chunk & 7;
      int sl = sp ^ (row & 7);
      gload_lds16(A + (size_t)(m0+row)*K + k0 + sl*8, &As[(t*256 + w*64)*8]);
      gload_lds16(Bt + (size_t)(n0+row)*K + k0 + sl*8, &Bs[(t*256 + w*64)*8]);
    }
    __syncthreads();
    #pragma unroll
    for (int s = 0; s < 2; ++s) {
      short8 af[4], bfr[4];
      #pragma unroll
      for (int mi = 0; mi < 4; ++mi) {
        int row = wr*64 + mi*16 + l15;
        int slot = (s*4 + l4) ^ (row & 7);
        af[mi] = *reinterpret_cast<const short8*>(&As[row*64 + slot*8]);
      }
      #pragma unroll
      for (int ni = 0; ni < 4; ++ni) {
        int row = wc*64 + ni*16 + l15;
        int slot = (s*4 + l4) ^ (row & 7);
        bfr[ni] = *reinterpret_cast<const short8*>(&Bs[row*64 + slot*8]);
      }
      #pragma unroll
      for (int mi = 0; mi < 4; ++mi)
        #pragma unroll
        for (int ni = 0; ni < 4; ++ni)
          acc[mi][ni] = __builtin_amdgcn_mfma_f32_16x16x32_bf16(af[mi], bfr[ni], acc[mi][ni], 0, 0, 0);
    }
    __syncthreads();
  }
  // epilogue: C row=(l>>4)*4+r, col=l&15 per 16x16 frag
  #pragma unroll
  for (int mi = 0; mi < 4; ++mi) {
    #pragma unroll
    for (int ni = 0; ni < 4; ++ni) {
      #pragma unroll
      for (int r = 0; r < 4; ++r) {
        int row = m0 + wr*64 + mi*16 + l4*4 + r;
        int col = n0 + wc*64 + ni*16 + l15;
        float v = acc[mi][ni][r];
        if (OUTMODE == 0) {
          v += bias[col];
          ((unsigned short*)Cout)[(size_t)row*N + col] = f2bf(v);
        } else {
          ((float*)Cout)[(size_t)row*N + col] = v;
        }
      }
    }
  }
}

// ---------------- RoPE + layout ----------------
// qkv [TOK][1152] bf16 -> Qr [B][NH][S][64] (x0.125), Kr [B][NKVH][S][64], Vt [B][NKVH][64][S]
__global__ void k_rope(const unsigned short* __restrict__ qkv,
                       const float* __restrict__ ct, const float* __restrict__ st,
                       unsigned short* __restrict__ Qr, unsigned short* __restrict__ Kr,
                       unsigned short* __restrict__ Vt) {
  int t = blockIdx.x; int b = t >> 11; int s = t & 2047;
  int tid = threadIdx.x;
  const unsigned short* row = qkv + (size_t)t * NQKV;
  if (tid < 448) {
    int h = tid >> 5, dp = tid & 31;
    float x1 = bf2f(row[h*64 + dp]);
    float x2 = bf2f(row[h*64 + dp + 32]);
    float c = ct[s*32 + dp], sn = st[s*32 + dp];
    size_t base = (((size_t)b*NH + h)*SEQ + s)*64;
    Qr[base + dp]      = f2bf((x1*c - x2*sn) * 0.125f);
    Qr[base + dp + 32] = f2bf((x2*c + x1*sn) * 0.125f);
  } else {
    int j = tid - 448;
    int kvh = j >> 5, dp = j & 31;
    float x1 = bf2f(row[NQ + kvh*64 + dp]);
    float x2 = bf2f(row[NQ + kvh*64 + dp + 32]);
    float c = ct[s*32 + dp], sn = st[s*32 + dp];
    size_t base = (((size_t)b*NKVH + kvh)*SEQ + s)*64;
    Kr[base + dp]      = f2bf(x1*c - x2*sn);
    Kr[base + dp + 32] = f2bf(x2*c + x1*sn);
  }
  if (tid < 128) {
    int kvh = tid >> 6, d = tid & 63;
    Vt[(((size_t)b*NKVH + kvh)*64 + d)*SEQ + s] = row[1024 + kvh*64 + d];
  }
}

// ---------------- flash attention (causal, GQA) ----------------
// 4 waves/block, wave w owns q-rows [qt*64+w*16, +16).
// K/V tiles double-buffered in LDS (shared across waves, prefetched via global_load_lds).
// P_lds is wave-private: no barriers needed around it.
__global__ __launch_bounds__(256, 4) void k_attn(
    const unsigned short* __restrict__ Q,   // [B][NH][S][64], pre-scaled by 0.125
    const unsigned short* __restrict__ Kr,  // [B][NKVH][S][64]
    const unsigned short* __restrict__ Vt,  // [B][NKVH][64][S]
    unsigned short* __restrict__ Aout) {    // [TOK][896]
  __shared__ __align__(16) unsigned short Kst[2][64*64];  // 16 KB
  __shared__ __align__(16) unsigned short Vst[2][64*64];  // 16 KB
  __shared__ __align__(16) unsigned short P_lds[4*16*64]; // 8 KB, 2 KB per wave
  int lane = threadIdx.x & 63, w = threadIdx.x >> 6;
  int l15 = lane & 15, l4 = lane >> 4;
  int qt = (int)gridDim.x - 1 - (int)blockIdx.x;   // heavy blocks first
  int h = blockIdx.y, b = blockIdx.z;
  int kvh = h / GQ;
  const unsigned short* Qb = Q + (((size_t)(b*NH + h))*SEQ + qt*64 + w*16) * 64;
  const unsigned short* Kb = Kr + ((size_t)(b*NKVH + kvh))*SEQ*64;
  const unsigned short* Vb = Vt + ((size_t)(b*NKVH + kvh))*64*SEQ;

  // stage K-tile + V^T-tile kt into buffer bsel; pre-swizzled source, linear LDS dest
  auto stage = [&](int kt, int bsel) {
    #pragma unroll
    for (int t = 0; t < 2; ++t) {
      int chunk = t*256 + w*64 + lane;
      int row = chunk >> 3;
      int sl = (chunk & 7) ^ (row & 7);
      gload_lds16(Kb + (size_t)(kt*64 + row)*64 + sl*8, &Kst[bsel][(t*256 + w*64)*8]);
      gload_lds16(Vb + (size_t)row*SEQ + kt*64 + sl*8, &Vst[bsel][(t*256 + w*64)*8]);
    }
  };

  short8 qa[2];
  #pragma unroll
  for (int s = 0; s < 2; ++s)
    qa[s] = *reinterpret_cast<const short8*>(Qb + l15*64 + s*32 + l4*8);

  f32x4 acc_o[4];
  #pragma unroll
  for (int n = 0; n < 4; ++n) acc_o[n] = fzero4();
  float m_run[4], l_run[4];
  #pragma unroll
  for (int r = 0; r < 4; ++r) { m_run[r] = -__builtin_inff(); l_run[r] = 0.0f; }

  unsigned short* Pw = &P_lds[w*16*64];
  int q_glob = qt*64 + w*16 + l4*4;   // + r

  int nkt = qt + 1;
  stage(0, 0);
  __syncthreads();   // drains vmcnt: buf0 ready
  int cur = 0;

  for (int kt = 0; kt < nkt; ++kt) {
    if (kt + 1 < nkt) stage(kt + 1, cur ^ 1);   // prefetch next tile
    // scores: S = Q(16x64) @ K^T(64x64) -> 4 col-frags, K from LDS (swizzled)
    f32x4 sa[4];
    #pragma unroll
    for (int n = 0; n < 4; ++n) sa[n] = fzero4();
    #pragma unroll
    for (int s = 0; s < 2; ++s) {
      short8 kb[4];
      #pragma unroll
      for (int n = 0; n < 4; ++n) {
        int row = n*16 + l15;
        int slot = (s*4 + l4) ^ (row & 7);
        kb[n] = *reinterpret_cast<const short8*>(&Kst[cur][row*64 + slot*8]);
      }
      #pragma unroll
      for (int n = 0; n < 4; ++n)
        sa[n] = __builtin_amdgcn_mfma_f32_16x16x32_bf16(qa[s], kb[n], sa[n], 0, 0, 0);
    }
    if (kt == qt) {  // diagonal tile: causal mask
      #pragma unroll
      for (int n = 0; n < 4; ++n) {
        int kc = kt*64 + n*16 + l15;
        #pragma unroll
        for (int r = 0; r < 4; ++r)
          if (kc > q_glob + r) sa[n][r] = -1e30f;
      }
    }
    // online softmax (wave-parallel, width-16 shuffle reduce) + P -> LDS (bf16, swizzled)
    #pragma unroll
    for (int r = 0; r < 4; ++r) {
      float tmax = fmaxf(fmaxf(sa[0][r], sa[1][r]), fmaxf(sa[2][r], sa[3][r]));
      tmax = fmaxf(tmax, __shfl_xor(tmax, 1, 16));
      tmax = fmaxf(tmax, __shfl_xor(tmax, 2, 16));
      tmax = fmaxf(tmax, __shfl_xor(tmax, 4, 16));
      tmax = fmaxf(tmax, __shfl_xor(tmax, 8, 16));
      float mn = fmaxf(m_run[r], tmax);
      float sc = __expf(m_run[r] - mn);
      float pv[4]; float sum = 0.0f;
      #pragma unroll
      for (int n = 0; n < 4; ++n) { pv[n] = __expf(sa[n][r] - mn); sum += pv[n]; }
      sum += __shfl_xor(sum, 1, 16);
      sum += __shfl_xor(sum, 2, 16);
      sum += __shfl_xor(sum, 4, 16);
      sum += __shfl_xor(sum, 8, 16);
      m_run[r] = mn;
      l_run[r] = l_run[r]*sc + sum;
      #pragma unroll
      for (int n = 0; n < 4; ++n) acc_o[n][r] *= sc;
      int prow = l4*4 + r;
      #pragma unroll
      for (int n = 0; n < 4; ++n) {
        int colbyte = n*32 + l15*2;
        int pb = prow*128 + ((((colbyte >> 4) ^ (prow & 7))) << 4) + (colbyte & 15);
        Pw[pb >> 1] = f2bf(pv[n]);
      }
    }
    // PV: O += P(16x64) @ V(64x64); A-frags from wave-private swizzled LDS, B from Vst
    #pragma unroll
    for (int s2 = 0; s2 < 2; ++s2) {
      int slot = (s2*4 + l4) ^ (l15 & 7);
      short8 pa = *reinterpret_cast<const short8*>(&Pw[(l15*128 + (slot << 4)) >> 1]);
      #pragma unroll
      for (int n = 0; n < 4; ++n) {
        int row = n*16 + l15;
        int vslot = (s2*4 + l4) ^ (row & 7);
        short8 vb = *reinterpret_cast<const short8*>(&Vst[cur][row*64 + vslot*8]);
        acc_o[n] = __builtin_amdgcn_mfma_f32_16x16x32_bf16(pa, vb, acc_o[n], 0, 0, 0);
      }
    }
    __syncthreads();   // drains vmcnt(prefetch) + all waves done with buf cur
    cur ^= 1;
  }
  // epilogue
  #pragma unroll
  for (int r = 0; r < 4; ++r) {
    float inv = 1.0f / l_run[r];
    size_t tok = (size_t)b*SEQ + q_glob + r;
    #pragma unroll
    for (int n = 0; n < 4; ++n)
      Aout[tok*NQ + h*64 + n*16 + l15] = f2bf(acc_o[n][r] * inv);
  }
}

// ---------------- launcher ----------------
extern "C" void kernel_launch(void* const* d_in, const int* in_sizes, int n_in,
                              void* d_out, int out_size, void* d_ws, size_t ws_size,
                              hipStream_t stream) {
  const float* hs = (const float*)d_in[0];
  const float* wq = (const float*)d_in[1];
  const float* bq = (const float*)d_in[2];
  const float* wk = (const float*)d_in[3];
  const float* bk = (const float*)d_in[4];
  const float* wv = (const float*)d_in[5];
  const float* bv = (const float*)d_in[6];
  const float* wo = (const float*)d_in[7];
  float* out = (float*)d_out;

  char* p = (char*)d_ws;
  auto alloc = [&](size_t bytes) { char* r = p; p += (bytes + 255) & ~(size_t)255; return r; };
  unsigned short* hb    = (unsigned short*)alloc((size_t)TOK*HID*2);
  unsigned short* wqkvt = (unsigned short*)alloc((size_t)NQKV*HID*2);
  unsigned short* wot   = (unsigned short*)alloc((size_t)HID*NQ*2);
  float*          bqkv  = (float*)alloc(NQKV*4);
  unsigned short* qkvt  = (unsigned short*)alloc((size_t)TOK*NQKV*2);
  unsigned short* q_r   = (unsigned short*)alloc((size_t)BATCH*NH*SEQ*DH*2);
  unsigned short* k_r   = (unsigned short*)alloc((size_t)BATCH*NKVH*SEQ*DH*2);
  unsigned short* v_t   = (unsigned short*)alloc((size_t)BATCH*NKVH*DH*SEQ*2);
  float*          ct    = (float*)alloc((size_t)SEQ*32*4);
  float*          st    = (float*)alloc((size_t)SEQ*32*4);
  unsigned short* attn  = hb;  // reuse: hb dead after GEMM1

  k_cvt<<<TOK*HID/4/256, 256, 0, stream>>>((const float4*)hs, (us4*)hb, TOK*HID/4);
  k_transpose_cvt<<<dim3(NQ/64, HID/64), 256, 0, stream>>>(wq, wqkvt, HID, NQ);
  k_transpose_cvt<<<dim3(NKV/64, HID/64), 256, 0, stream>>>(wk, wqkvt + (size_t)NQ*HID, HID, NKV);
  k_transpose_cvt<<<dim3(NKV/64, HID/64), 256, 0, stream>>>(wv, wqkvt + (size_t)(NQ+NKV)*HID, HID, NKV);
  k_transpose_cvt<<<dim3(HID/64, NQ/64), 256, 0, stream>>>(wo, wot, NQ, HID);
  k_bias<<<5, 256, 0, stream>>>(bq, bk, bv, bqkv);
  k_tables<<<SEQ*32/256, 256, 0, stream>>>(ct, st);

  k_gemm_bt<0><<<dim3(NQKV/128, TOK/128), 256, 0, stream>>>(hb, wqkvt, bqkv, qkvt, TOK, NQKV, HID);
  k_rope<<<TOK, 512, 0, stream>>>(qkvt, ct, st, q_r, k_r, v_t);
  k_attn<<<dim3(SEQ/64, NH, BATCH), 256, 0, stream>>>(q_r, k_r, v_t, attn);
  k_gemm_bt<1><<<dim3(NQ/128, TOK/128), 256, 0, stream>>>(attn, wot, nullptr, out, TOK, NQ, HID);
}

// Round 3
// 117.235 us; speedup vs baseline: 2.9357x; 1.4984x over previous
//
#include <hip/hip_runtime.h>

#define HID 896
#define NQ 896
#define NKV 128
#define NQKV 1152
#define NH 14
#define NKVH 2
#define GQ 7
#define DH 64
#define SEQ 2048
#define BATCH 2
#define TOK (BATCH*SEQ)

typedef __attribute__((ext_vector_type(8))) short short8;    // 8 bf16 (4 VGPRs)
typedef __attribute__((ext_vector_type(4))) float f32x4;
typedef __attribute__((ext_vector_type(4))) unsigned short us4;

__device__ __forceinline__ unsigned short f2bf(float x) {
  unsigned int u = __builtin_bit_cast(unsigned int, x);
  u = (u + 0x7fffu + ((u >> 16) & 1u)) >> 16;
  return (unsigned short)u;
}
__device__ __forceinline__ float bf2f(unsigned short b) {
  return __builtin_bit_cast(float, (unsigned int)b << 16);
}
__device__ __forceinline__ f32x4 fzero4() {
  f32x4 z; z[0]=0.f; z[1]=0.f; z[2]=0.f; z[3]=0.f; return z;
}
__device__ __forceinline__ unsigned int cvt_pk_bf16(float lo, float hi) {
  unsigned int r;
  asm("v_cvt_pk_bf16_f32 %0, %1, %2" : "=v"(r) : "v"(lo), "v"(hi));
  return r;
}
__device__ __forceinline__ void gload_lds16(const unsigned short* g, unsigned short* l) {
  __builtin_amdgcn_global_load_lds(
      (const __attribute__((address_space(1))) void*)(const void*)g,
      (__attribute__((address_space(3))) void*)(void*)l, 16, 0, 0);
}

// ---------------- conversion kernels ----------------

__global__ void k_cvt(const float4* __restrict__ in, us4* __restrict__ out, int n4) {
  int i = blockIdx.x * blockDim.x + threadIdx.x;
  if (i >= n4) return;
  float4 v = in[i];
  us4 o; o[0]=f2bf(v.x); o[1]=f2bf(v.y); o[2]=f2bf(v.z); o[3]=f2bf(v.w);
  out[i] = o;
}

// W [K][N] fp32 -> out [N][K] bf16, 64x64 tiles via LDS
__global__ void k_transpose_cvt(const float* __restrict__ W, unsigned short* __restrict__ out,
                                int K, int N) {
  __shared__ unsigned short Ls[64*65];
  int n0 = blockIdx.x * 64, k0 = blockIdx.y * 64;
  int tid = threadIdx.x;
  #pragma unroll
  for (int i = 0; i < 16; ++i) {
    int idx = i*256 + tid;
    int r = idx >> 6, c = idx & 63;
    Ls[c*65 + r] = f2bf(W[(size_t)(k0 + r)*N + n0 + c]);
  }
  __syncthreads();
  #pragma unroll
  for (int i = 0; i < 16; ++i) {
    int idx = i*256 + tid;
    int r2 = idx >> 6, c2 = idx & 63;
    out[(size_t)(n0 + r2)*K + k0 + c2] = Ls[r2*65 + c2];
  }
}

__global__ void k_bias(const float* __restrict__ bq, const float* __restrict__ bk,
                       const float* __restrict__ bv, float* __restrict__ out) {
  int i = blockIdx.x * blockDim.x + threadIdx.x;
  if (i >= NQKV) return;
  if (i < NQ) out[i] = bq[i];
  else if (i < NQ + NKV) out[i] = bk[i - NQ];
  else out[i] = bv[i - NQ - NKV];
}

__global__ void k_tables(float* __restrict__ ct, float* __restrict__ st) {
  int i = blockIdx.x * blockDim.x + threadIdx.x;  // SEQ*32
  int s = i >> 5, dp = i & 31;
  float inv = __expf(-(float)(2*dp) * (13.815510557964274f / 64.0f)); // theta^(-2dp/64)
  float f = (float)s * inv;
  ct[i] = cosf(f); st[i] = sinf(f);
}

// ---------------- GEMM: C[M][N] = A[M][K] @ Bt[N][K]^T (bf16 in, fp32 acc) ----------------
// OUTMODE 0: bf16 out + bias; OUTMODE 1: fp32 out
template<int OUTMODE>
__global__ __launch_bounds__(256, 2) void k_gemm_bt(
    const unsigned short* __restrict__ A,
    const unsigned short* __restrict__ Bt,
    const float* __restrict__ bias,
    void* __restrict__ Cout,
    int M, int N, int K) {
  __shared__ unsigned short As[128*64];
  __shared__ unsigned short Bs[128*64];
  int tid = threadIdx.x;
  int lane = tid & 63, w = tid >> 6;
  int wr = w >> 1, wc = w & 1;
  int l15 = lane & 15, l4 = lane >> 4;
  int m0 = blockIdx.y * 128, n0 = blockIdx.x * 128;

  f32x4 acc[4][4];
  #pragma unroll
  for (int i = 0; i < 4; ++i)
    #pragma unroll
    for (int j = 0; j < 4; ++j) acc[i][j] = fzero4();

  int nkt = K >> 6;
  for (int kt = 0; kt < nkt; ++kt) {
    int k0 = kt << 6;
    #pragma unroll
    for (int t = 0; t < 4; ++t) {
      int chunk = t*256 + w*64 + lane;
      int row = chunk >> 3, sp = chunk & 7;
      int sl = sp ^ (row & 7);
      gload_lds16(A + (size_t)(m0+row)*K + k0 + sl*8, &As[(t*256 + w*64)*8]);
      gload_lds16(Bt + (size_t)(n0+row)*K + k0 + sl*8, &Bs[(t*256 + w*64)*8]);
    }
    __syncthreads();
    #pragma unroll
    for (int s = 0; s < 2; ++s) {
      short8 af[4], bfr[4];
      #pragma unroll
      for (int mi = 0; mi < 4; ++mi) {
        int row = wr*64 + mi*16 + l15;
        int slot = (s*4 + l4) ^ (row & 7);
        af[mi] = *reinterpret_cast<const short8*>(&As[row*64 + slot*8]);
      }
      #pragma unroll
      for (int ni = 0; ni < 4; ++ni) {
        int row = wc*64 + ni*16 + l15;
        int slot = (s*4 + l4) ^ (row & 7);
        bfr[ni] = *reinterpret_cast<const short8*>(&Bs[row*64 + slot*8]);
      }
      #pragma unroll
      for (int mi = 0; mi < 4; ++mi)
        #pragma unroll
        for (int ni = 0; ni < 4; ++ni)
          acc[mi][ni] = __builtin_amdgcn_mfma_f32_16x16x32_bf16(af[mi], bfr[ni], acc[mi][ni], 0, 0, 0);
    }
    __syncthreads();
  }
  #pragma unroll
  for (int mi = 0; mi < 4; ++mi) {
    #pragma unroll
    for (int ni = 0; ni < 4; ++ni) {
      #pragma unroll
      for (int r = 0; r < 4; ++r) {
        int row = m0 + wr*64 + mi*16 + l4*4 + r;
        int col = n0 + wc*64 + ni*16 + l15;
        float v = acc[mi][ni][r];
        if (OUTMODE == 0) {
          v += bias[col];
          ((unsigned short*)Cout)[(size_t)row*N + col] = f2bf(v);
        } else {
          ((float*)Cout)[(size_t)row*N + col] = v;
        }
      }
    }
  }
}

// ---------------- RoPE + layout ----------------
__global__ void k_rope(const unsigned short* __restrict__ qkv,
                       const float* __restrict__ ct, const float* __restrict__ st,
                       unsigned short* __restrict__ Qr, unsigned short* __restrict__ Kr,
                       unsigned short* __restrict__ Vt) {
  int t = blockIdx.x; int b = t >> 11; int s = t & 2047;
  int tid = threadIdx.x;
  const unsigned short* row = qkv + (size_t)t * NQKV;
  if (tid < 448) {
    int h = tid >> 5, dp = tid & 31;
    float x1 = bf2f(row[h*64 + dp]);
    float x2 = bf2f(row[h*64 + dp + 32]);
    float c = ct[s*32 + dp], sn = st[s*32 + dp];
    size_t base = (((size_t)b*NH + h)*SEQ + s)*64;
    Qr[base + dp]      = f2bf((x1*c - x2*sn) * 0.125f);
    Qr[base + dp + 32] = f2bf((x2*c + x1*sn) * 0.125f);
  } else {
    int j = tid - 448;
    int kvh = j >> 5, dp = j & 31;
    float x1 = bf2f(row[NQ + kvh*64 + dp]);
    float x2 = bf2f(row[NQ + kvh*64 + dp + 32]);
    float c = ct[s*32 + dp], sn = st[s*32 + dp];
    size_t base = (((size_t)b*NKVH + kvh)*SEQ + s)*64;
    Kr[base + dp]      = f2bf(x1*c - x2*sn);
    Kr[base + dp + 32] = f2bf(x2*c + x1*sn);
  }
  if (tid < 128) {
    int kvh = tid >> 6, d = tid & 63;
    Vt[(((size_t)b*NKVH + kvh)*64 + d)*SEQ + s] = row[1024 + kvh*64 + d];
  }
}

// ---------------- flash attention (causal, GQA) ----------------
// Paired q-tiles (heavy 31-i, light i) share one staged K/V stream: light's
// k-range is a prefix of heavy's. Every block = exactly 33 tile-computes.
// Swapped QK^T (S^T, q=l15) -> in-lane softmax (2 shuffles), packed b64 P writes,
// transposed PV (O^T, q=l15) -> per-lane rescale, O transposed back via LDS at end.
__global__ __launch_bounds__(256, 2) void k_attn(
    const unsigned short* __restrict__ Q,   // [B][NH][S][64], pre-scaled by 0.125
    const unsigned short* __restrict__ Kr,  // [B][NKVH][S][64]
    const unsigned short* __restrict__ Vt,  // [B][NKVH][64][S]
    unsigned short* __restrict__ Aout) {    // [TOK][896]
  __shared__ __align__(16) unsigned short Kst[2][64*64];   // 16 KB
  __shared__ __align__(16) unsigned short Vst[2][64*64];   // 16 KB
  __shared__ __align__(16) unsigned short P_lds[2][4*16*64]; // 16 KB: [tile][wave][16q][64k]
  int lane = threadIdx.x & 63, w = threadIdx.x >> 6;
  int l15 = lane & 15, l4 = lane >> 4;
  int i = blockIdx.x, h = blockIdx.y, b = blockIdx.z;
  int qtH = 31 - i, qtL = i;
  int kvh = h / GQ;
  const unsigned short* Kb = Kr + ((size_t)(b*NKVH + kvh))*SEQ*64;
  const unsigned short* Vb = Vt + ((size_t)(b*NKVH + kvh))*64*SEQ;
  char* PwH = (char*)&P_lds[0][w*16*64];
  char* PwL = (char*)&P_lds[1][w*16*64];

  auto stage = [&](int kt, int bsel) {
    #pragma unroll
    for (int t = 0; t < 2; ++t) {
      int chunk = t*256 + w*64 + lane;
      int row = chunk >> 3;
      int sl = (chunk & 7) ^ (row & 7);
      gload_lds16(Kb + (size_t)(kt*64 + row)*64 + sl*8, &Kst[bsel][(t*256 + w*64)*8]);
      gload_lds16(Vb + (size_t)row*SEQ + kt*64 + sl*8, &Vst[bsel][(t*256 + w*64)*8]);
    }
  };

  const unsigned short* QbH = Q + (((size_t)(b*NH + h))*SEQ + qtH*64 + w*16) * 64;
  const unsigned short* QbL = Q + (((size_t)(b*NH + h))*SEQ + qtL*64 + w*16) * 64;
  short8 qaH[2], qaL[2];
  #pragma unroll
  for (int s = 0; s < 2; ++s) {
    qaH[s] = *reinterpret_cast<const short8*>(QbH + l15*64 + s*32 + l4*8);
    qaL[s] = *reinterpret_cast<const short8*>(QbL + l15*64 + s*32 + l4*8);
  }

  f32x4 accH[4], accL[4];
  #pragma unroll
  for (int n = 0; n < 4; ++n) { accH[n] = fzero4(); accL[n] = fzero4(); }
  float mH = -__builtin_inff(), lH = 0.0f;
  float mL = -__builtin_inff(), lL = 0.0f;

  int cur = 0;

  // one k-tile step for one q-tile: swapped QK^T, in-lane softmax, packed P, transposed PV
  auto tile = [&](int kt, bool diag, short8 (&qa)[2], f32x4 (&acc)[4],
                  float& m_run, float& l_run, int qt, char* Pwb) {
    f32x4 sa[4];
    #pragma unroll
    for (int n = 0; n < 4; ++n) sa[n] = fzero4();
    #pragma unroll
    for (int s = 0; s < 2; ++s) {
      short8 kb[4];
      #pragma unroll
      for (int n = 0; n < 4; ++n) {
        int row = n*16 + l15;
        int slot = (s*4 + l4) ^ (row & 7);
        kb[n] = *reinterpret_cast<const short8*>(&Kst[cur][row*64 + slot*8]);
      }
      #pragma unroll
      for (int n = 0; n < 4; ++n)   // swapped: A=K-frag, B=Q-frag -> S^T[k][q], q=l15
        sa[n] = __builtin_amdgcn_mfma_f32_16x16x32_bf16(kb[n], qa[s], sa[n], 0, 0, 0);
    }
    if (diag) {
      int q_glob = qt*64 + w*16 + l15;
      #pragma unroll
      for (int n = 0; n < 4; ++n)
        #pragma unroll
        for (int r = 0; r < 4; ++r) {
          int kpos = kt*64 + n*16 + l4*4 + r;
          if (kpos > q_glob) sa[n][r] = -1e30f;
        }
    }
    // in-lane max over 16, then 2 shuffles across l4
    float t01 = fmaxf(fmaxf(sa[0][0],sa[0][1]), fmaxf(sa[0][2],sa[0][3]));
    float t11 = fmaxf(fmaxf(sa[1][0],sa[1][1]), fmaxf(sa[1][2],sa[1][3]));
    float t21 = fmaxf(fmaxf(sa[2][0],sa[2][1]), fmaxf(sa[2][2],sa[2][3]));
    float t31 = fmaxf(fmaxf(sa[3][0],sa[3][1]), fmaxf(sa[3][2],sa[3][3]));
    float tmax = fmaxf(fmaxf(t01,t11), fmaxf(t21,t31));
    tmax = fmaxf(tmax, __shfl_xor(tmax, 16));
    tmax = fmaxf(tmax, __shfl_xor(tmax, 32));
    float mn = fmaxf(m_run, tmax);
    float sc = __expf(m_run - mn);
    #pragma unroll
    for (int n = 0; n < 4; ++n)
      #pragma unroll
      for (int r = 0; r < 4; ++r) sa[n][r] = __expf(sa[n][r] - mn);
    float s0 = (sa[0][0]+sa[0][1]) + (sa[0][2]+sa[0][3]);
    float s1 = (sa[1][0]+sa[1][1]) + (sa[1][2]+sa[1][3]);
    float s2r = (sa[2][0]+sa[2][1]) + (sa[2][2]+sa[2][3]);
    float s3 = (sa[3][0]+sa[3][1]) + (sa[3][2]+sa[3][3]);
    float sum = (s0+s1) + (s2r+s3);
    sum += __shfl_xor(sum, 16);
    sum += __shfl_xor(sum, 32);
    m_run = mn;
    l_run = l_run*sc + sum;
    #pragma unroll
    for (int n = 0; n < 4; ++n) acc[n] *= sc;
    // pack P (4 contiguous k per frag) -> swizzled b64 writes
    #pragma unroll
    for (int n = 0; n < 4; ++n) {
      uint2 pk;
      pk.x = cvt_pk_bf16(sa[n][0], sa[n][1]);
      pk.y = cvt_pk_bf16(sa[n][2], sa[n][3]);
      int colbyte = n*32 + l4*8;
      int addr = l15*128 + ((((colbyte>>4) ^ (l15&7))) << 4) + (colbyte & 15);
      *reinterpret_cast<uint2*>(Pwb + addr) = pk;
    }
    // PV transposed: A=V^T-frag, B=P-frag -> O^T[d][q], q=l15
    #pragma unroll
    for (int s2 = 0; s2 < 2; ++s2) {
      int pslot = (s2*4 + l4) ^ (l15 & 7);
      short8 pa = *reinterpret_cast<const short8*>(Pwb + l15*128 + pslot*16);
      #pragma unroll
      for (int n = 0; n < 4; ++n) {
        int row = n*16 + l15;
        int vslot = (s2*4 + l4) ^ (row & 7);
        short8 vb = *reinterpret_cast<const short8*>(&Vst[cur][row*64 + vslot*8]);
        acc[n] = __builtin_amdgcn_mfma_f32_16x16x32_bf16(vb, pa, acc[n], 0, 0, 0);
      }
    }
  };

  stage(0, 0);
  __syncthreads();
  int nkt = qtH + 1;
  for (int kt = 0; kt < nkt; ++kt) {
    if (kt + 1 < nkt) stage(kt + 1, cur ^ 1);
    tile(kt, kt == qtH, qaH, accH, mH, lH, qtH, PwH);
    if (kt <= qtL) tile(kt, kt == qtL, qaL, accL, mL, lL, qtL, PwL);
    __syncthreads();
    cur ^= 1;
  }

  // epilogue: normalize, transpose O^T -> O via wave-private LDS, coalesced write
  auto epi = [&](f32x4 (&acc)[4], float l_run, int qt, char* Pwb) {
    float inv = 1.0f / l_run;
    #pragma unroll
    for (int n = 0; n < 4; ++n) {
      uint2 pk;
      pk.x = cvt_pk_bf16(acc[n][0]*inv, acc[n][1]*inv);
      pk.y = cvt_pk_bf16(acc[n][2]*inv, acc[n][3]*inv);
      int colbyte = n*32 + l4*8;
      int addr = l15*128 + ((((colbyte>>4) ^ (l15&7))) << 4) + (colbyte & 15);
      *reinterpret_cast<uint2*>(Pwb + addr) = pk;
    }
    int row = lane >> 2;
    int cb0 = (lane & 3) * 32;
    #pragma unroll
    for (int it = 0; it < 2; ++it) {
      int cb = cb0 + it*16;
      int slot = (cb >> 4) ^ (row & 7);
      short8 v = *reinterpret_cast<const short8*>(Pwb + row*128 + slot*16);
      size_t tok = (size_t)b*SEQ + qt*64 + w*16 + row;
      *reinterpret_cast<short8*>(&Aout[tok*NQ + h*64 + (cb>>1)]) = v;
    }
  };
  epi(accH, lH, qtH, PwH);
  epi(accL, lL, qtL, PwL);
}

// ---------------- launcher ----------------
extern "C" void kernel_launch(void* const* d_in, const int* in_sizes, int n_in,
                              void* d_out, int out_size, void* d_ws, size_t ws_size,
                              hipStream_t stream) {
  const float* hs = (const float*)d_in[0];
  const float* wq = (const float*)d_in[1];
  const float* bq = (const float*)d_in[2];
  const float* wk = (const float*)d_in[3];
  const float* bk = (const float*)d_in[4];
  const float* wv = (const float*)d_in[5];
  const float* bv = (const float*)d_in[6];
  const float* wo = (const float*)d_in[7];
  float* out = (float*)d_out;

  char* p = (char*)d_ws;
  auto alloc = [&](size_t bytes) { char* r = p; p += (bytes + 255) & ~(size_t)255; return r; };
  unsigned short* hb    = (unsigned short*)alloc((size_t)TOK*HID*2);
  unsigned short* wqkvt = (unsigned short*)alloc((size_t)NQKV*HID*2);
  unsigned short* wot   = (unsigned short*)alloc((size_t)HID*NQ*2);
  float*          bqkv  = (float*)alloc(NQKV*4);
  unsigned short* qkvt  = (unsigned short*)alloc((size_t)TOK*NQKV*2);
  unsigned short* q_r   = (unsigned short*)alloc((size_t)BATCH*NH*SEQ*DH*2);
  unsigned short* k_r   = (unsigned short*)alloc((size_t)BATCH*NKVH*SEQ*DH*2);
  unsigned short* v_t   = (unsigned short*)alloc((size_t)BATCH*NKVH*DH*SEQ*2);
  float*          ct    = (float*)alloc((size_t)SEQ*32*4);
  float*          st    = (float*)alloc((size_t)SEQ*32*4);
  unsigned short* attn  = hb;  // reuse: hb dead after GEMM1

  k_cvt<<<TOK*HID/4/256, 256, 0, stream>>>((const float4*)hs, (us4*)hb, TOK*HID/4);
  k_transpose_cvt<<<dim3(NQ/64, HID/64), 256, 0, stream>>>(wq, wqkvt, HID, NQ);
  k_transpose_cvt<<<dim3(NKV/64, HID/64), 256, 0, stream>>>(wk, wqkvt + (size_t)NQ*HID, HID, NKV);
  k_transpose_cvt<<<dim3(NKV/64, HID/64), 256, 0, stream>>>(wv, wqkvt + (size_t)(NQ+NKV)*HID, HID, NKV);
  k_transpose_cvt<<<dim3(HID/64, NQ/64), 256, 0, stream>>>(wo, wot, NQ, HID);
  k_bias<<<5, 256, 0, stream>>>(bq, bk, bv, bqkv);
  k_tables<<<SEQ*32/256, 256, 0, stream>>>(ct, st);

  k_gemm_bt<0><<<dim3(NQKV/128, TOK/128), 256, 0, stream>>>(hb, wqkvt, bqkv, qkvt, TOK, NQKV, HID);
  k_rope<<<TOK, 512, 0, stream>>>(qkvt, ct, st, q_r, k_r, v_t);
  k_attn<<<dim3(16, NH, BATCH), 256, 0, stream>>>(q_r, k_r, v_t, attn);
  k_gemm_bt<1><<<dim3(NQ/128, TOK/128), 256, 0, stream>>>(attn, wot, nullptr, out, TOK, NQ, HID);
}

// Round 6
// 104.090 us; speedup vs baseline: 3.3065x; 1.1263x over previous
//
#include <hip/hip_runtime.h>

#define HID 896
#define NQ 896
#define NKV 128
#define NQKV 1152
#define NH 14
#define NKVH 2
#define GQ 7
#define DH 64
#define SEQ 2048
#define BATCH 2
#define TOK (BATCH*SEQ)

typedef __attribute__((ext_vector_type(8))) short short8;    // 8 bf16 (4 VGPRs)
typedef __attribute__((ext_vector_type(4))) float f32x4;
typedef __attribute__((ext_vector_type(4))) unsigned short us4;

__device__ __forceinline__ unsigned short f2bf(float x) {
  unsigned int u = __builtin_bit_cast(unsigned int, x);
  u = (u + 0x7fffu + ((u >> 16) & 1u)) >> 16;
  return (unsigned short)u;
}
__device__ __forceinline__ float bf2f(unsigned short b) {
  return __builtin_bit_cast(float, (unsigned int)b << 16);
}
__device__ __forceinline__ f32x4 fzero4() {
  f32x4 z; z[0]=0.f; z[1]=0.f; z[2]=0.f; z[3]=0.f; return z;
}
__device__ __forceinline__ unsigned int cvt_pk_bf16(float lo, float hi) {
  unsigned int r;
  asm("v_cvt_pk_bf16_f32 %0, %1, %2" : "=v"(r) : "v"(lo), "v"(hi));
  return r;
}
__device__ __forceinline__ void gload_lds16(const unsigned short* g, unsigned short* l) {
  __builtin_amdgcn_global_load_lds(
      (const __attribute__((address_space(1))) void*)(const void*)g,
      (__attribute__((address_space(3))) void*)(void*)l, 16, 0, 0);
}

// ---------------- fused prep: cvt + 4 weight transposes + bias + rope tables ----------------
#define CVT_BLKS 3584   // TOK*HID/4/256
#define TRN_BLKS 448    // 196 (wq) + 28 (wk) + 28 (wv) + 196 (wo)
#define BIAS_BLKS 5
#define TAB_BLKS 256
#define PREP_BLKS (CVT_BLKS + TRN_BLKS + BIAS_BLKS + TAB_BLKS)

__global__ void k_prep(const float* __restrict__ hs,
                       const float* __restrict__ wq, const float* __restrict__ bq,
                       const float* __restrict__ wk, const float* __restrict__ bk,
                       const float* __restrict__ wv, const float* __restrict__ bv,
                       const float* __restrict__ wo,
                       unsigned short* __restrict__ hb,
                       unsigned short* __restrict__ wqkvt,
                       unsigned short* __restrict__ wot,
                       float* __restrict__ bqkv,
                       float* __restrict__ ct, float* __restrict__ st) {
  __shared__ unsigned short Ls[64*65];
  int blk = blockIdx.x, tid = threadIdx.x;
  if (blk < CVT_BLKS) {  // hidden fp32 -> bf16
    int i = blk*256 + tid;
    float4 v = ((const float4*)hs)[i];
    us4 o; o[0]=f2bf(v.x); o[1]=f2bf(v.y); o[2]=f2bf(v.z); o[3]=f2bf(v.w);
    ((us4*)hb)[i] = o;
    return;
  }
  blk -= CVT_BLKS;
  if (blk < TRN_BLKS) {  // W [K][N] fp32 -> out [N][K] bf16, 64x64 tile
    const float* W; unsigned short* out; int K, N, n0, k0;
    if (blk < 196)      { W=wq; out=wqkvt;                        K=HID; N=NQ;  int t=blk;     n0=(t%14)*64; k0=(t/14)*64; }
    else if (blk < 224) { W=wk; out=wqkvt + (size_t)NQ*HID;       K=HID; N=NKV; int t=blk-196; n0=(t%2)*64;  k0=(t/2)*64; }
    else if (blk < 252) { W=wv; out=wqkvt + (size_t)(NQ+NKV)*HID; K=HID; N=NKV; int t=blk-224; n0=(t%2)*64;  k0=(t/2)*64; }
    else                { W=wo; out=wot;                          K=NQ;  N=HID; int t=blk-252; n0=(t%14)*64; k0=(t/14)*64; }
    #pragma unroll
    for (int i = 0; i < 16; ++i) {
      int idx = i*256 + tid;
      int r = idx >> 6, c = idx & 63;
      Ls[c*65 + r] = f2bf(W[(size_t)(k0 + r)*N + n0 + c]);
    }
    __syncthreads();
    #pragma unroll
    for (int i = 0; i < 16; ++i) {
      int idx = i*256 + tid;
      int r2 = idx >> 6, c2 = idx & 63;
      out[(size_t)(n0 + r2)*K + k0 + c2] = Ls[r2*65 + c2];
    }
    return;
  }
  blk -= TRN_BLKS;
  if (blk < BIAS_BLKS) {
    int i = blk*256 + tid;
    if (i < NQKV) {
      if (i < NQ) bqkv[i] = bq[i];
      else if (i < NQ + NKV) bqkv[i] = bk[i - NQ];
      else bqkv[i] = bv[i - NQ - NKV];
    }
    return;
  }
  blk -= BIAS_BLKS;
  {  // rope tables, SEQ*32 entries
    int i = blk*256 + tid;
    int s = i >> 5, dp = i & 31;
    float inv = __expf(-(float)(2*dp) * (13.815510557964274f / 64.0f));
    float f = (float)s * inv;
    ct[i] = cosf(f); st[i] = sinf(f);
  }
}

// ---------------- GEMM: C[M][N] = A[M][K] @ Bt[N][K]^T (bf16 in, fp32 acc) ----------------
// OUTMODE 0: bf16 out + bias; OUTMODE 1: fp32 out
template<int OUTMODE>
__global__ __launch_bounds__(256, 2) void k_gemm_bt(
    const unsigned short* __restrict__ A,
    const unsigned short* __restrict__ Bt,
    const float* __restrict__ bias,
    void* __restrict__ Cout,
    int M, int N, int K) {
  __shared__ unsigned short As[128*64];
  __shared__ unsigned short Bs[128*64];
  int tid = threadIdx.x;
  int lane = tid & 63, w = tid >> 6;
  int wr = w >> 1, wc = w & 1;
  int l15 = lane & 15, l4 = lane >> 4;
  int m0 = blockIdx.y * 128, n0 = blockIdx.x * 128;

  f32x4 acc[4][4];
  #pragma unroll
  for (int i = 0; i < 4; ++i)
    #pragma unroll
    for (int j = 0; j < 4; ++j) acc[i][j] = fzero4();

  int nkt = K >> 6;
  for (int kt = 0; kt < nkt; ++kt) {
    int k0 = kt << 6;
    #pragma unroll
    for (int t = 0; t < 4; ++t) {
      int chunk = t*256 + w*64 + lane;
      int row = chunk >> 3, sp = chunk & 7;
      int sl = sp ^ (row & 7);
      gload_lds16(A + (size_t)(m0+row)*K + k0 + sl*8, &As[(t*256 + w*64)*8]);
      gload_lds16(Bt + (size_t)(n0+row)*K + k0 + sl*8, &Bs[(t*256 + w*64)*8]);
    }
    __syncthreads();
    #pragma unroll
    for (int s = 0; s < 2; ++s) {
      short8 af[4], bfr[4];
      #pragma unroll
      for (int mi = 0; mi < 4; ++mi) {
        int row = wr*64 + mi*16 + l15;
        int slot = (s*4 + l4) ^ (row & 7);
        af[mi] = *reinterpret_cast<const short8*>(&As[row*64 + slot*8]);
      }
      #pragma unroll
      for (int ni = 0; ni < 4; ++ni) {
        int row = wc*64 + ni*16 + l15;
        int slot = (s*4 + l4) ^ (row & 7);
        bfr[ni] = *reinterpret_cast<const short8*>(&Bs[row*64 + slot*8]);
      }
      #pragma unroll
      for (int mi = 0; mi < 4; ++mi)
        #pragma unroll
        for (int ni = 0; ni < 4; ++ni)
          acc[mi][ni] = __builtin_amdgcn_mfma_f32_16x16x32_bf16(af[mi], bfr[ni], acc[mi][ni], 0, 0, 0);
    }
    __syncthreads();
  }
  #pragma unroll
  for (int mi = 0; mi < 4; ++mi) {
    #pragma unroll
    for (int ni = 0; ni < 4; ++ni) {
      #pragma unroll
      for (int r = 0; r < 4; ++r) {
        int row = m0 + wr*64 + mi*16 + l4*4 + r;
        int col = n0 + wc*64 + ni*16 + l15;
        float v = acc[mi][ni][r];
        if (OUTMODE == 0) {
          v += bias[col];
          ((unsigned short*)Cout)[(size_t)row*N + col] = f2bf(v);
        } else {
          ((float*)Cout)[(size_t)row*N + col] = v;
        }
      }
    }
  }
}

// ---------------- RoPE + layout ----------------
__global__ void k_rope(const unsigned short* __restrict__ qkv,
                       const float* __restrict__ ct, const float* __restrict__ st,
                       unsigned short* __restrict__ Qr, unsigned short* __restrict__ Kr,
                       unsigned short* __restrict__ Vt) {
  int t = blockIdx.x; int b = t >> 11; int s = t & 2047;
  int tid = threadIdx.x;
  const unsigned short* row = qkv + (size_t)t * NQKV;
  if (tid < 448) {
    int h = tid >> 5, dp = tid & 31;
    float x1 = bf2f(row[h*64 + dp]);
    float x2 = bf2f(row[h*64 + dp + 32]);
    float c = ct[s*32 + dp], sn = st[s*32 + dp];
    size_t base = (((size_t)b*NH + h)*SEQ + s)*64;
    Qr[base + dp]      = f2bf((x1*c - x2*sn) * 0.125f);
    Qr[base + dp + 32] = f2bf((x2*c + x1*sn) * 0.125f);
  } else {
    int j = tid - 448;
    int kvh = j >> 5, dp = j & 31;
    float x1 = bf2f(row[NQ + kvh*64 + dp]);
    float x2 = bf2f(row[NQ + kvh*64 + dp + 32]);
    float c = ct[s*32 + dp], sn = st[s*32 + dp];
    size_t base = (((size_t)b*NKVH + kvh)*SEQ + s)*64;
    Kr[base + dp]      = f2bf(x1*c - x2*sn);
    Kr[base + dp + 32] = f2bf(x2*c + x1*sn);
  }
  if (tid < 128) {
    int kvh = tid >> 6, d = tid & 63;
    Vt[(((size_t)b*NKVH + kvh)*64 + d)*SEQ + s] = row[1024 + kvh*64 + d];
  }
}

// ---------------- flash attention (causal, GQA) — R3's exact paired version ----------------
__global__ __launch_bounds__(256, 2) void k_attn(
    const unsigned short* __restrict__ Q,   // [B][NH][S][64], pre-scaled by 0.125
    const unsigned short* __restrict__ Kr,  // [B][NKVH][S][64]
    const unsigned short* __restrict__ Vt,  // [B][NKVH][64][S]
    unsigned short* __restrict__ Aout) {    // [TOK][896]
  __shared__ __align__(16) unsigned short Kst[2][64*64];   // 16 KB
  __shared__ __align__(16) unsigned short Vst[2][64*64];   // 16 KB
  __shared__ __align__(16) unsigned short P_lds[2][4*16*64]; // 16 KB: [tile][wave][16q][64k]
  int lane = threadIdx.x & 63, w = threadIdx.x >> 6;
  int l15 = lane & 15, l4 = lane >> 4;
  int i = blockIdx.x, h = blockIdx.y, b = blockIdx.z;
  int qtH = 31 - i, qtL = i;
  int kvh = h / GQ;
  const unsigned short* Kb = Kr + ((size_t)(b*NKVH + kvh))*SEQ*64;
  const unsigned short* Vb = Vt + ((size_t)(b*NKVH + kvh))*64*SEQ;
  char* PwH = (char*)&P_lds[0][w*16*64];
  char* PwL = (char*)&P_lds[1][w*16*64];

  auto stage = [&](int kt, int bsel) {
    #pragma unroll
    for (int t = 0; t < 2; ++t) {
      int chunk = t*256 + w*64 + lane;
      int row = chunk >> 3;
      int sl = (chunk & 7) ^ (row & 7);
      gload_lds16(Kb + (size_t)(kt*64 + row)*64 + sl*8, &Kst[bsel][(t*256 + w*64)*8]);
      gload_lds16(Vb + (size_t)row*SEQ + kt*64 + sl*8, &Vst[bsel][(t*256 + w*64)*8]);
    }
  };

  const unsigned short* QbH = Q + (((size_t)(b*NH + h))*SEQ + qtH*64 + w*16) * 64;
  const unsigned short* QbL = Q + (((size_t)(b*NH + h))*SEQ + qtL*64 + w*16) * 64;
  short8 qaH[2], qaL[2];
  #pragma unroll
  for (int s = 0; s < 2; ++s) {
    qaH[s] = *reinterpret_cast<const short8*>(QbH + l15*64 + s*32 + l4*8);
    qaL[s] = *reinterpret_cast<const short8*>(QbL + l15*64 + s*32 + l4*8);
  }

  f32x4 accH[4], accL[4];
  #pragma unroll
  for (int n = 0; n < 4; ++n) { accH[n] = fzero4(); accL[n] = fzero4(); }
  float mH = -__builtin_inff(), lH = 0.0f;
  float mL = -__builtin_inff(), lL = 0.0f;

  int cur = 0;

  auto tile = [&](int kt, bool diag, short8 (&qa)[2], f32x4 (&acc)[4],
                  float& m_run, float& l_run, int qt, char* Pwb) {
    f32x4 sa[4];
    #pragma unroll
    for (int n = 0; n < 4; ++n) sa[n] = fzero4();
    #pragma unroll
    for (int s = 0; s < 2; ++s) {
      short8 kb[4];
      #pragma unroll
      for (int n = 0; n < 4; ++n) {
        int row = n*16 + l15;
        int slot = (s*4 + l4) ^ (row & 7);
        kb[n] = *reinterpret_cast<const short8*>(&Kst[cur][row*64 + slot*8]);
      }
      #pragma unroll
      for (int n = 0; n < 4; ++n)   // swapped: A=K-frag, B=Q-frag -> S^T[k][q], q=l15
        sa[n] = __builtin_amdgcn_mfma_f32_16x16x32_bf16(kb[n], qa[s], sa[n], 0, 0, 0);
    }
    if (diag) {
      int q_glob = qt*64 + w*16 + l15;
      #pragma unroll
      for (int n = 0; n < 4; ++n)
        #pragma unroll
        for (int r = 0; r < 4; ++r) {
          int kpos = kt*64 + n*16 + l4*4 + r;
          if (kpos > q_glob) sa[n][r] = -1e30f;
        }
    }
    float t01 = fmaxf(fmaxf(sa[0][0],sa[0][1]), fmaxf(sa[0][2],sa[0][3]));
    float t11 = fmaxf(fmaxf(sa[1][0],sa[1][1]), fmaxf(sa[1][2],sa[1][3]));
    float t21 = fmaxf(fmaxf(sa[2][0],sa[2][1]), fmaxf(sa[2][2],sa[2][3]));
    float t31 = fmaxf(fmaxf(sa[3][0],sa[3][1]), fmaxf(sa[3][2],sa[3][3]));
    float tmax = fmaxf(fmaxf(t01,t11), fmaxf(t21,t31));
    tmax = fmaxf(tmax, __shfl_xor(tmax, 16));
    tmax = fmaxf(tmax, __shfl_xor(tmax, 32));
    float mn = fmaxf(m_run, tmax);
    float sc = __expf(m_run - mn);
    #pragma unroll
    for (int n = 0; n < 4; ++n)
      #pragma unroll
      for (int r = 0; r < 4; ++r) sa[n][r] = __expf(sa[n][r] - mn);
    float s0 = (sa[0][0]+sa[0][1]) + (sa[0][2]+sa[0][3]);
    float s1 = (sa[1][0]+sa[1][1]) + (sa[1][2]+sa[1][3]);
    float s2r = (sa[2][0]+sa[2][1]) + (sa[2][2]+sa[2][3]);
    float s3 = (sa[3][0]+sa[3][1]) + (sa[3][2]+sa[3][3]);
    float sum = (s0+s1) + (s2r+s3);
    sum += __shfl_xor(sum, 16);
    sum += __shfl_xor(sum, 32);
    m_run = mn;
    l_run = l_run*sc + sum;
    #pragma unroll
    for (int n = 0; n < 4; ++n) acc[n] *= sc;
    #pragma unroll
    for (int n = 0; n < 4; ++n) {
      uint2 pk;
      pk.x = cvt_pk_bf16(sa[n][0], sa[n][1]);
      pk.y = cvt_pk_bf16(sa[n][2], sa[n][3]);
      int colbyte = n*32 + l4*8;
      int addr = l15*128 + ((((colbyte>>4) ^ (l15&7))) << 4) + (colbyte & 15);
      *reinterpret_cast<uint2*>(Pwb + addr) = pk;
    }
    #pragma unroll
    for (int s2 = 0; s2 < 2; ++s2) {
      int pslot = (s2*4 + l4) ^ (l15 & 7);
      short8 pa = *reinterpret_cast<const short8*>(Pwb + l15*128 + pslot*16);
      #pragma unroll
      for (int n = 0; n < 4; ++n) {
        int row = n*16 + l15;
        int vslot = (s2*4 + l4) ^ (row & 7);
        short8 vb = *reinterpret_cast<const short8*>(&Vst[cur][row*64 + vslot*8]);
        acc[n] = __builtin_amdgcn_mfma_f32_16x16x32_bf16(vb, pa, acc[n], 0, 0, 0);
      }
    }
  };

  stage(0, 0);
  __syncthreads();
  int nkt = qtH + 1;
  for (int kt = 0; kt < nkt; ++kt) {
    if (kt + 1 < nkt) stage(kt + 1, cur ^ 1);
    tile(kt, kt == qtH, qaH, accH, mH, lH, qtH, PwH);
    if (kt <= qtL) tile(kt, kt == qtL, qaL, accL, mL, lL, qtL, PwL);
    __syncthreads();
    cur ^= 1;
  }

  auto epi = [&](f32x4 (&acc)[4], float l_run, int qt, char* Pwb) {
    float inv = 1.0f / l_run;
    #pragma unroll
    for (int n = 0; n < 4; ++n) {
      uint2 pk;
      pk.x = cvt_pk_bf16(acc[n][0]*inv, acc[n][1]*inv);
      pk.y = cvt_pk_bf16(acc[n][2]*inv, acc[n][3]*inv);
      int colbyte = n*32 + l4*8;
      int addr = l15*128 + ((((colbyte>>4) ^ (l15&7))) << 4) + (colbyte & 15);
      *reinterpret_cast<uint2*>(Pwb + addr) = pk;
    }
    int row = lane >> 2;
    int cb0 = (lane & 3) * 32;
    #pragma unroll
    for (int it = 0; it < 2; ++it) {
      int cb = cb0 + it*16;
      int slot = (cb >> 4) ^ (row & 7);
      short8 v = *reinterpret_cast<const short8*>(Pwb + row*128 + slot*16);
      size_t tok = (size_t)b*SEQ + qt*64 + w*16 + row;
      *reinterpret_cast<short8*>(&Aout[tok*NQ + h*64 + (cb>>1)]) = v;
    }
  };
  epi(accH, lH, qtH, PwH);
  epi(accL, lL, qtL, PwL);
}

// ---------------- launcher ----------------
extern "C" void kernel_launch(void* const* d_in, const int* in_sizes, int n_in,
                              void* d_out, int out_size, void* d_ws, size_t ws_size,
                              hipStream_t stream) {
  const float* hs = (const float*)d_in[0];
  const float* wq = (const float*)d_in[1];
  const float* bq = (const float*)d_in[2];
  const float* wk = (const float*)d_in[3];
  const float* bk = (const float*)d_in[4];
  const float* wv = (const float*)d_in[5];
  const float* bv = (const float*)d_in[6];
  const float* wo = (const float*)d_in[7];
  float* out = (float*)d_out;

  char* p = (char*)d_ws;
  auto alloc = [&](size_t bytes) { char* r = p; p += (bytes + 255) & ~(size_t)255; return r; };
  unsigned short* hb    = (unsigned short*)alloc((size_t)TOK*HID*2);
  unsigned short* wqkvt = (unsigned short*)alloc((size_t)NQKV*HID*2);
  unsigned short* wot   = (unsigned short*)alloc((size_t)HID*NQ*2);
  float*          bqkv  = (float*)alloc(NQKV*4);
  unsigned short* qkvt  = (unsigned short*)alloc((size_t)TOK*NQKV*2);
  unsigned short* q_r   = (unsigned short*)alloc((size_t)BATCH*NH*SEQ*DH*2);
  unsigned short* k_r   = (unsigned short*)alloc((size_t)BATCH*NKVH*SEQ*DH*2);
  unsigned short* v_t   = (unsigned short*)alloc((size_t)BATCH*NKVH*DH*SEQ*2);
  float*          ct    = (float*)alloc((size_t)SEQ*32*4);
  float*          st    = (float*)alloc((size_t)SEQ*32*4);
  unsigned short* attn  = hb;  // reuse: hb dead after GEMM1

  k_prep<<<PREP_BLKS, 256, 0, stream>>>(hs, wq, bq, wk, bk, wv, bv, wo,
                                        hb, wqkvt, wot, bqkv, ct, st);
  k_gemm_bt<0><<<dim3(NQKV/128, TOK/128), 256, 0, stream>>>(hb, wqkvt, bqkv, qkvt, TOK, NQKV, HID);
  k_rope<<<TOK, 512, 0, stream>>>(qkvt, ct, st, q_r, k_r, v_t);
  k_attn<<<dim3(16, NH, BATCH), 256, 0, stream>>>(q_r, k_r, v_t, attn);
  k_gemm_bt<1><<<dim3(NQ/128, TOK/128), 256, 0, stream>>>(attn, wot, nullptr, out, TOK, NQ, HID);
}